// Round 1
// baseline (495.325 us; speedup 1.0000x reference)
//
#include <hip/hip_runtime.h>
#include <stdint.h>

#define L_SEQ 2048
#define DMODEL 1024
#define NHEAD 16
#define HDIM 64
#define BATCH 2

typedef __attribute__((ext_vector_type(8))) short bf16x8;
typedef __attribute__((ext_vector_type(4))) float f32x4;

#define MFMA(a, b, c) __builtin_amdgcn_mfma_f32_16x16x32_bf16((a), (b), (c), 0, 0, 0)

__device__ __forceinline__ unsigned short f2bf(float f) {
    unsigned int x = __float_as_uint(f);
    unsigned int r = (x + 0x7fffu + ((x >> 16) & 1u)) >> 16;
    return (unsigned short)r;
}
__device__ __forceinline__ float bf2f(unsigned short h) {
    return __uint_as_float(((unsigned int)h) << 16);
}

// ---------------------------------------------------------------------------
// Kernel A: C = X @ W^T + bias (NT GEMM, fp32 in, bf16 MFMA), optional RoPE,
// writes bf16 in (b, n, l, h) layout.
// Tile: 128x128, BK=32, 4 waves (2x2), each wave 64x64 = 4x4 MFMA 16x16x32.
// ---------------------------------------------------------------------------
__global__ __launch_bounds__(256) void qkv_rope_kernel(
    const float* __restrict__ X, const float* __restrict__ W,
    const float* __restrict__ bias, unsigned short* __restrict__ dst,
    const int do_rope)
{
    __shared__ unsigned short As[128 * 40];  // +8 pad: 2-way bank aliasing (free)
    __shared__ unsigned short Bs[128 * 40];

    const int tid  = threadIdx.x;
    const int wave = tid >> 6, lane = tid & 63;
    const int ml = lane & 15, kq = lane >> 4;
    const int m0 = blockIdx.y * 128, n0 = blockIdx.x * 128;
    const int wm = (wave & 1) * 64, wn = (wave >> 1) * 64;

    f32x4 acc[4][4];
#pragma unroll
    for (int i = 0; i < 4; ++i)
#pragma unroll
        for (int j = 0; j < 4; ++j) acc[i][j] = (f32x4){0.f, 0.f, 0.f, 0.f};

    const int sr = tid >> 3;         // 0..31
    const int sc = (tid & 7) * 4;    // 0..28

    for (int kc = 0; kc < DMODEL; kc += 32) {
#pragma unroll
        for (int p = 0; p < 4; ++p) {
            const int row = sr + 32 * p;
            const float4 va = *(const float4*)(X + (size_t)(m0 + row) * DMODEL + kc + sc);
            unsigned short* sa = &As[row * 40 + sc];
            sa[0] = f2bf(va.x); sa[1] = f2bf(va.y); sa[2] = f2bf(va.z); sa[3] = f2bf(va.w);
            const float4 vb = *(const float4*)(W + (size_t)(n0 + row) * DMODEL + kc + sc);
            unsigned short* sb = &Bs[row * 40 + sc];
            sb[0] = f2bf(vb.x); sb[1] = f2bf(vb.y); sb[2] = f2bf(vb.z); sb[3] = f2bf(vb.w);
        }
        __syncthreads();

        bf16x8 af[4], bfr[4];
#pragma unroll
        for (int i = 0; i < 4; ++i)
            af[i] = *(const bf16x8*)&As[(wm + i * 16 + ml) * 40 + kq * 8];
#pragma unroll
        for (int j = 0; j < 4; ++j)
            bfr[j] = *(const bf16x8*)&Bs[(wn + j * 16 + ml) * 40 + kq * 8];
#pragma unroll
        for (int i = 0; i < 4; ++i)
#pragma unroll
            for (int j = 0; j < 4; ++j)
                acc[i][j] = MFMA(af[i], bfr[j], acc[i][j]);
        __syncthreads();
    }

    // Epilogue: bias, RoPE (interleaved pairs via shfl_xor lane^1), bf16 store.
#pragma unroll
    for (int jt = 0; jt < 4; ++jt) {
        const int col = n0 + wn + jt * 16 + ml;   // output feature index
        const float bv = bias[col];
        const int nh = col >> 6, hh = col & 63;
        // inv_freq = 10000^(-(2t)/64), t = hh/2
        const float inv_freq = powf(10000.0f, -(float)(hh & 62) * (1.0f / 64.0f));
#pragma unroll
        for (int it = 0; it < 4; ++it) {
#pragma unroll
            for (int r = 0; r < 4; ++r) {
                const int row = m0 + wm + it * 16 + kq * 4 + r;  // b*L + l
                const int bb = row >> 11, ll = row & 2047;
                const float v = acc[it][jt][r] + bv;
                const float partner = __shfl_xor(v, 1);  // value at col^1 (has its own bias)
                float res = v;
                if (do_rope) {
                    float sn, cs;
                    sincosf((float)ll * inv_freq, &sn, &cs);
                    // even col: x*cos - x_odd*sin ; odd col: x*cos + x_even*sin
                    res = (hh & 1) ? fmaf(v, cs, partner * sn)
                                   : fmaf(v, cs, -partner * sn);
                }
                dst[(((size_t)(bb * NHEAD + nh) * L_SEQ + ll) << 6) + hh] = f2bf(res);
            }
        }
    }
}

// ---------------------------------------------------------------------------
// Kernel B: flash attention. Block = 64 q-rows of one (b, head); 4 waves,
// each wave owns 16 q-rows. Key tiles of 64. bf16 MFMA, fp32 online softmax.
// ---------------------------------------------------------------------------
__global__ __launch_bounds__(256) void attn_kernel(
    const unsigned short* __restrict__ Qr, const unsigned short* __restrict__ Kr,
    const unsigned short* __restrict__ Vr, const int* __restrict__ mask,
    float* __restrict__ AO)
{
    __shared__ unsigned short Ks[64 * 72];      // [key][h], pad to 72
    __shared__ unsigned short Vs[64 * 72];      // transposed: [h][key]
    __shared__ unsigned short Ps[4 * 16 * 72];  // per-wave P tile [m][key]

    const int tid  = threadIdx.x;
    const int wave = tid >> 6, lane = tid & 63;
    const int ml = lane & 15, kq = lane >> 4;
    const int bh = blockIdx.y;          // b*16 + n
    const int b  = bh >> 4;
    const int q0 = blockIdx.x * 64;

    const unsigned short* Qp = Qr + ((size_t)bh * L_SEQ + q0) * HDIM;
    const unsigned short* Kp = Kr + (size_t)bh * L_SEQ * HDIM;
    const unsigned short* Vp = Vr + (size_t)bh * L_SEQ * HDIM;
    const int* mp = mask + b * L_SEQ;

    const int wrow = wave * 16;
    // Q fragments for this wave's 16 rows (A-layout), loaded once from global.
    const bf16x8 aq0 = *(const bf16x8*)(Qp + (wrow + ml) * HDIM + kq * 8);
    const bf16x8 aq1 = *(const bf16x8*)(Qp + (wrow + ml) * HDIM + 32 + kq * 8);

    float mi[4], li[4];
    f32x4 o[4];
#pragma unroll
    for (int r = 0; r < 4; ++r) { mi[r] = -INFINITY; li[r] = 0.f; }
#pragma unroll
    for (int ht = 0; ht < 4; ++ht) o[ht] = (f32x4){0.f, 0.f, 0.f, 0.f};

    const int skey = tid >> 2;          // 0..63
    const int sh   = (tid & 3) * 16;    // 0,16,32,48

    for (int kt = 0; kt < L_SEQ / 64; ++kt) {
        // ---- stage K (row-major) and V (transposed) ----
        {
            const unsigned short* krow = Kp + ((size_t)(kt * 64 + skey)) * HDIM + sh;
            *(uint4*)&Ks[skey * 72 + sh]     = *(const uint4*)(krow);
            *(uint4*)&Ks[skey * 72 + sh + 8] = *(const uint4*)(krow + 8);
            const unsigned short* vrow = Vp + ((size_t)(kt * 64 + skey)) * HDIM + sh;
            union { uint4 u; unsigned short s[8]; } v0, v1;
            v0.u = *(const uint4*)(vrow);
            v1.u = *(const uint4*)(vrow + 8);
#pragma unroll
            for (int j = 0; j < 8; ++j) {
                Vs[(sh + j) * 72 + skey]     = v0.s[j];
                Vs[(sh + 8 + j) * 72 + skey] = v1.s[j];
            }
        }
        __syncthreads();

        // ---- S = Q K^T : 16 rows x 64 keys per wave ----
        f32x4 s[4];
#pragma unroll
        for (int nt = 0; nt < 4; ++nt) {
            const bf16x8 bk0 = *(const bf16x8*)&Ks[(nt * 16 + ml) * 72 + kq * 8];
            const bf16x8 bk1 = *(const bf16x8*)&Ks[(nt * 16 + ml) * 72 + 32 + kq * 8];
            f32x4 c = (f32x4){0.f, 0.f, 0.f, 0.f};
            c = MFMA(aq0, bk0, c);
            c = MFMA(aq1, bk1, c);
            s[nt] = c;
        }

        // ---- scale + mask ----
        float pv[4][4];
#pragma unroll
        for (int nt = 0; nt < 4; ++nt) {
            const int key = kt * 64 + nt * 16 + ml;
            const bool msk = (mp[key] != 0);
#pragma unroll
            for (int r = 0; r < 4; ++r)
                pv[nt][r] = msk ? -1.0e8f : s[nt][r] * 0.03125f;  // 1/sqrt(D)=1/32
        }

        // ---- online softmax update (per row r, 16 lanes share a row) ----
#pragma unroll
        for (int r = 0; r < 4; ++r) {
            float rm = fmaxf(fmaxf(pv[0][r], pv[1][r]), fmaxf(pv[2][r], pv[3][r]));
#pragma unroll
            for (int off = 1; off < 16; off <<= 1)
                rm = fmaxf(rm, __shfl_xor(rm, off));
            const float mnew = fmaxf(mi[r], rm);
            const float alpha = __expf(mi[r] - mnew);
            mi[r] = mnew;
            float rs = 0.f;
#pragma unroll
            for (int nt = 0; nt < 4; ++nt) {
                pv[nt][r] = __expf(pv[nt][r] - mnew);
                rs += pv[nt][r];
            }
#pragma unroll
            for (int off = 1; off < 16; off <<= 1)
                rs += __shfl_xor(rs, off);
            li[r] = li[r] * alpha + rs;
#pragma unroll
            for (int ht = 0; ht < 4; ++ht) o[ht][r] *= alpha;
        }

        // ---- P (C-layout) -> LDS -> A-layout ----
        unsigned short* Pw = &Ps[wave * 16 * 72];
#pragma unroll
        for (int nt = 0; nt < 4; ++nt)
#pragma unroll
            for (int r = 0; r < 4; ++r)
                Pw[(kq * 4 + r) * 72 + nt * 16 + ml] = f2bf(pv[nt][r]);
        __syncthreads();

        const bf16x8 ap0 = *(const bf16x8*)(Pw + ml * 72 + kq * 8);
        const bf16x8 ap1 = *(const bf16x8*)(Pw + ml * 72 + 32 + kq * 8);
#pragma unroll
        for (int ht = 0; ht < 4; ++ht) {
            const bf16x8 bv0 = *(const bf16x8*)&Vs[(ht * 16 + ml) * 72 + kq * 8];
            const bf16x8 bv1 = *(const bf16x8*)&Vs[(ht * 16 + ml) * 72 + 32 + kq * 8];
            o[ht] = MFMA(ap0, bv0, o[ht]);
            o[ht] = MFMA(ap1, bv1, o[ht]);
        }
        __syncthreads();
    }

    // ---- epilogue: normalize, write fp32 (b, l, n*64+h) ----
    const int nh = bh & 15;
#pragma unroll
    for (int ht = 0; ht < 4; ++ht) {
#pragma unroll
        for (int r = 0; r < 4; ++r) {
            const int l = q0 + wrow + kq * 4 + r;
            const int col = nh * 64 + ht * 16 + ml;
            AO[((size_t)b * L_SEQ + l) * DMODEL + col] = o[ht][r] / li[r];
        }
    }
}

// ---------------------------------------------------------------------------
// Kernel C: out = X @ Wo^T + bo, fp32 in/out, 3-term bf16-split MFMA
// (hi*hi + lo*hi + hi*lo) for near-fp32 accuracy.
// ---------------------------------------------------------------------------
__global__ __launch_bounds__(256) void oproj_kernel(
    const float* __restrict__ X, const float* __restrict__ W,
    const float* __restrict__ bias, float* __restrict__ out)
{
    __shared__ unsigned short Ah[128 * 40], Al[128 * 40];
    __shared__ unsigned short Bh[128 * 40], Bl[128 * 40];

    const int tid  = threadIdx.x;
    const int wave = tid >> 6, lane = tid & 63;
    const int ml = lane & 15, kq = lane >> 4;
    const int m0 = blockIdx.y * 128, n0 = blockIdx.x * 128;
    const int wm = (wave & 1) * 64, wn = (wave >> 1) * 64;

    f32x4 acc[4][4];
#pragma unroll
    for (int i = 0; i < 4; ++i)
#pragma unroll
        for (int j = 0; j < 4; ++j) acc[i][j] = (f32x4){0.f, 0.f, 0.f, 0.f};

    const int sr = tid >> 3;
    const int sc = (tid & 7) * 4;

    for (int kc = 0; kc < DMODEL; kc += 32) {
#pragma unroll
        for (int p = 0; p < 4; ++p) {
            const int row = sr + 32 * p;
            const float4 va = *(const float4*)(X + (size_t)(m0 + row) * DMODEL + kc + sc);
            const float4 vb = *(const float4*)(W + (size_t)(n0 + row) * DMODEL + kc + sc);
            const float fa[4] = {va.x, va.y, va.z, va.w};
            const float fb[4] = {vb.x, vb.y, vb.z, vb.w};
#pragma unroll
            for (int qi = 0; qi < 4; ++qi) {
                const unsigned short ha = f2bf(fa[qi]);
                Ah[row * 40 + sc + qi] = ha;
                Al[row * 40 + sc + qi] = f2bf(fa[qi] - bf2f(ha));
                const unsigned short hb = f2bf(fb[qi]);
                Bh[row * 40 + sc + qi] = hb;
                Bl[row * 40 + sc + qi] = f2bf(fb[qi] - bf2f(hb));
            }
        }
        __syncthreads();

        bf16x8 ah[4], al[4];
#pragma unroll
        for (int i = 0; i < 4; ++i) {
            ah[i] = *(const bf16x8*)&Ah[(wm + i * 16 + ml) * 40 + kq * 8];
            al[i] = *(const bf16x8*)&Al[(wm + i * 16 + ml) * 40 + kq * 8];
        }
#pragma unroll
        for (int j = 0; j < 4; ++j) {
            const bf16x8 bh_ = *(const bf16x8*)&Bh[(wn + j * 16 + ml) * 40 + kq * 8];
            const bf16x8 bl_ = *(const bf16x8*)&Bl[(wn + j * 16 + ml) * 40 + kq * 8];
#pragma unroll
            for (int i = 0; i < 4; ++i) {
                acc[i][j] = MFMA(ah[i], bh_, acc[i][j]);
                acc[i][j] = MFMA(al[i], bh_, acc[i][j]);
                acc[i][j] = MFMA(ah[i], bl_, acc[i][j]);
            }
        }
        __syncthreads();
    }

#pragma unroll
    for (int jt = 0; jt < 4; ++jt) {
        const int col = n0 + wn + jt * 16 + ml;
        const float bv = bias[col];
#pragma unroll
        for (int it = 0; it < 4; ++it)
#pragma unroll
            for (int r = 0; r < 4; ++r) {
                const int row = m0 + wm + it * 16 + kq * 4 + r;
                out[(size_t)row * DMODEL + col] = acc[it][jt][r] + bv;
            }
    }
}

extern "C" void kernel_launch(void* const* d_in, const int* in_sizes, int n_in,
                              void* d_out, int out_size, void* d_ws, size_t ws_size,
                              hipStream_t stream)
{
    (void)in_sizes; (void)n_in; (void)out_size; (void)ws_size;
    const float* q    = (const float*)d_in[0];
    const float* k    = (const float*)d_in[1];
    const float* v    = (const float*)d_in[2];
    const int*   mask = (const int*)d_in[3];
    const float* Wq   = (const float*)d_in[4];
    const float* bq   = (const float*)d_in[5];
    const float* Wk   = (const float*)d_in[6];
    const float* bk   = (const float*)d_in[7];
    const float* Wv   = (const float*)d_in[8];
    const float* bv   = (const float*)d_in[9];
    const float* Wo   = (const float*)d_in[10];
    const float* bo   = (const float*)d_in[11];
    float* out = (float*)d_out;

    const size_t HE = (size_t)BATCH * NHEAD * L_SEQ * HDIM;  // 4,194,304
    unsigned short* Qr = (unsigned short*)d_ws;
    unsigned short* Kr = Qr + HE;
    unsigned short* Vr = Kr + HE;
    float* AO = (float*)(Vr + HE);   // 16 MB fp32 (b, l, d); total ws = 40 MB

    dim3 blk(256);
    dim3 g1(DMODEL / 128, (BATCH * L_SEQ) / 128);   // 8 x 32
    qkv_rope_kernel<<<g1, blk, 0, stream>>>(q, Wq, bq, Qr, 1);
    qkv_rope_kernel<<<g1, blk, 0, stream>>>(k, Wk, bk, Kr, 1);
    qkv_rope_kernel<<<g1, blk, 0, stream>>>(v, Wv, bv, Vr, 0);

    dim3 g2(L_SEQ / 64, BATCH * NHEAD);             // 32 x 32
    attn_kernel<<<g2, blk, 0, stream>>>(Qr, Kr, Vr, mask, AO);

    dim3 g3(DMODEL / 128, (BATCH * L_SEQ) / 128);   // 8 x 32
    oproj_kernel<<<g3, blk, 0, stream>>>(AO, Wo, bo, out);
}